// Round 8
// baseline (2423.049 us; speedup 1.0000x reference)
//
#include <hip/hip_runtime.h>
#include <hip/hip_bf16.h>

#define NN 20000
#define EE 640000
#define HB 16                 // histogram/scatter blocks
#define CHUNK (EE / HB)       // 40000 edges per block

// WS budget: ~16 MB. Static total = 3,892,769 x 4B = 15.57 MB.
// hist/base (16x20000 ints each, 2.56 MB total) ALIAS hz (dead until
// spmm#1 writes it). zh/zl (bf16 split of z) alias h (dead after spmm#1).
// ws is re-poisoned between timed iterations (R6) -> no cross-iter state.
//
// CSR build is ATOMIC-FREE this round (R8 experiment): private per-block
// LDS histograms -> scan (off + per-block bases) -> scatter via LDS
// cursors. Zero device-scope atomics (R7 had 1.28M contended RMWs).
//
// Launch structure (6 launches):
//   L0: hist (16 blk, LDS-private) ∥ gemm1 (W12=W1@W2)
//   L1: scan -> off[] + base[16][N]
//   L2: scatter (16 blk, LDS cursor) ∥ gemm2 (h=feat@W12)
//   L3: spmm#1 (hz=A@h)
//   L4: spmm#2 (z=A@hz, emits zh/zl)
//   L5: decoder (Arec=sigmoid(z z^T))

typedef float f32x4 __attribute__((ext_vector_type(4)));
typedef short short8 __attribute__((ext_vector_type(8)));   // 8 bf16 = 4 VGPRs

__device__ __forceinline__ float sigf(float x) {
    return __builtin_amdgcn_rcpf(1.0f + __builtin_amdgcn_exp2f(x * -1.442695041f));
}

// ---- shared GEMM body: C[M,Nc] = A[M,K] @ B[K,Nc], 64-row tile (Nc<=64),
// 256 threads, 4x4 per thread. Whole block takes same branch -> uniform syncs.
__device__ void sgemm64_body(const float* __restrict__ A, const float* __restrict__ B,
                             float* __restrict__ C, int M, int K, int Nc, int by) {
    __shared__ float As[16][65];
    __shared__ float Bs[16][65];
    int tid = threadIdx.x;
    int tm = (tid >> 4) << 2;
    int tn = (tid & 15) << 2;
    int m0 = by * 64;
    float acc[4][4] = {};
    for (int k0 = 0; k0 < K; k0 += 16) {
        for (int i = tid; i < 64 * 16; i += 256) {
            int r = i >> 4, c = i & 15;
            int gr = m0 + r;
            As[c][r] = (gr < M) ? A[(long)gr * K + k0 + c] : 0.0f;
        }
        for (int i = tid; i < 16 * 64; i += 256) {
            int kk = i >> 6, c = i & 63;
            Bs[kk][c] = B[(long)(k0 + kk) * Nc + c];
        }
        __syncthreads();
        #pragma unroll
        for (int kk = 0; kk < 16; ++kk) {
            float a[4], b[4];
            #pragma unroll
            for (int x = 0; x < 4; ++x) a[x] = As[kk][tm + x];
            #pragma unroll
            for (int y = 0; y < 4; ++y) b[y] = Bs[kk][tn + y];
            #pragma unroll
            for (int x = 0; x < 4; ++x)
                #pragma unroll
                for (int y = 0; y < 4; ++y)
                    acc[x][y] = fmaf(a[x], b[y], acc[x][y]);
        }
        __syncthreads();
    }
    for (int x = 0; x < 4; ++x) {
        int gr = m0 + tm + x;
        if (gr < M) {
            #pragma unroll
            for (int y = 0; y < 4; ++y) C[(long)gr * Nc + tn + y] = acc[x][y];
        }
    }
}

// L0: blocks [0,16): private LDS histogram of a 40K-edge chunk -> hist[b][:].
//     blocks [16,24): gemm1 W12 = W1@W2 (M=512,K=256,Nc=64).
__global__ __launch_bounds__(256) void fused_hist_g1(const int* __restrict__ rows,
                                                     int* __restrict__ hist,
                                                     const float* __restrict__ W1,
                                                     const float* __restrict__ W2,
                                                     float* __restrict__ W12) {
    int blk = blockIdx.x;
    if (blk < HB) {
        __shared__ int lhist[NN];
        int tid = threadIdx.x;
        for (int i = tid; i < NN; i += 256) lhist[i] = 0;
        __syncthreads();
        int start = blk * CHUNK, end = start + CHUNK;
        for (int i = start + tid; i < end; i += 256)
            atomicAdd(&lhist[rows[i]], 1);          // LDS atomic — no fabric
        __syncthreads();
        int* hb = hist + (long)blk * NN;
        for (int i = tid; i < NN; i += 256) hb[i] = lhist[i];
    } else {
        sgemm64_body(W1, W2, W12, 512, 256, 64, blk - HB);
    }
}

// L1: single block, 1024 threads. off[bin] = exclusive prefix of total
// counts; base[b][bin] = off[bin] + sum_{b'<b} hist[b'][bin].
__global__ __launch_bounds__(1024) void scan_hist(const int* __restrict__ hist,
                                                  int* __restrict__ off,
                                                  int* __restrict__ base) {
    __shared__ int part[1024];
    int tid = threadIdx.x;
    const int per = (NN + 1023) / 1024;             // 20
    int b0 = tid * per;
    int s = 0;
    for (int i = 0; i < per; ++i) {
        int bin = b0 + i;
        if (bin < NN)
            for (int b = 0; b < HB; ++b) s += hist[(long)b * NN + bin];
    }
    part[tid] = s;
    __syncthreads();
    for (int d = 1; d < 1024; d <<= 1) {
        int v = (tid >= d) ? part[tid - d] : 0;
        __syncthreads();
        part[tid] += v;
        __syncthreads();
    }
    int run = (tid == 0) ? 0 : part[tid - 1];
    for (int i = 0; i < per; ++i) {
        int bin = b0 + i;
        if (bin < NN) {
            off[bin] = run;
            int acc = run;
            for (int b = 0; b < HB; ++b) {
                base[(long)b * NN + bin] = acc;
                acc += hist[(long)b * NN + bin];
            }
            run = acc;
        }
    }
    if (tid == 1023) off[NN] = part[1023];
}

// L2: blocks [0,16): scatter chunk edges using LDS cursors seeded from base.
//     blocks [16,329): gemm2 h = feat@W12 (M=20000,K=512,Nc=64).
__global__ __launch_bounds__(256) void fused_scatter_g2(const int* __restrict__ rows,
                                                        const int* __restrict__ cols,
                                                        const float* __restrict__ vals,
                                                        const int* __restrict__ base,
                                                        int* __restrict__ col_s,
                                                        float* __restrict__ val_s,
                                                        const float* __restrict__ feat,
                                                        const float* __restrict__ W12,
                                                        float* __restrict__ h) {
    int blk = blockIdx.x;
    if (blk < HB) {
        __shared__ int lcur[NN];
        int tid = threadIdx.x;
        const int* bb = base + (long)blk * NN;
        for (int i = tid; i < NN; i += 256) lcur[i] = bb[i];
        __syncthreads();
        int start = blk * CHUNK, end = start + CHUNK;
        for (int i = start + tid; i < end; i += 256) {
            int r = rows[i];
            int p = atomicAdd(&lcur[r], 1);         // LDS atomic — no fabric
            col_s[p] = cols[i];
            val_s[p] = vals[i];
        }
    } else {
        sgemm64_body(feat, W12, h, NN, 512, 64, blk - HB);
    }
}

// Y[row,:] = sum_e val[e] * X[col[e],:]; 4-way unrolled with independent
// partial accumulators. Optionally emits split-bf16 copy of the result.
__global__ __launch_bounds__(256) void spmm_csr64(const int* __restrict__ off,
                                                  const int* __restrict__ col_s,
                                                  const float* __restrict__ val_s,
                                                  const float* __restrict__ X,
                                                  float* __restrict__ Y,
                                                  __hip_bfloat16* __restrict__ ZH,
                                                  __hip_bfloat16* __restrict__ ZL, int n) {
    int row = blockIdx.x * 4 + (threadIdx.x >> 6);
    if (row >= n) return;
    int lane = threadIdx.x & 63;
    int e0 = off[row], e1 = off[row + 1];
    float a0 = 0.f, a1 = 0.f, a2 = 0.f, a3 = 0.f;
    int e = e0;
    for (; e + 4 <= e1; e += 4) {
        float v0 = val_s[e],     v1 = val_s[e + 1];
        float v2 = val_s[e + 2], v3 = val_s[e + 3];
        int   c0 = col_s[e],     c1 = col_s[e + 1];
        int   c2 = col_s[e + 2], c3 = col_s[e + 3];
        a0 = fmaf(v0, X[(long)c0 * 64 + lane], a0);
        a1 = fmaf(v1, X[(long)c1 * 64 + lane], a1);
        a2 = fmaf(v2, X[(long)c2 * 64 + lane], a2);
        a3 = fmaf(v3, X[(long)c3 * 64 + lane], a3);
    }
    for (; e < e1; ++e)
        a0 = fmaf(val_s[e], X[(long)col_s[e] * 64 + lane], a0);
    float acc = (a0 + a1) + (a2 + a3);
    Y[(long)row * 64 + lane] = acc;
    if (ZH) {
        __hip_bfloat16 hi = __float2bfloat16(acc);
        __hip_bfloat16 lo = __float2bfloat16(acc - __bfloat162float(hi));
        ZH[(long)row * 64 + lane] = hi;
        ZL[(long)row * 64 + lane] = lo;
    }
}

// A[i,j] = sigmoid(dot(Z[i],Z[j])) via bf16 MFMA, split representation
// (hi.hi + hi.lo + lo.hi). Block (bx,by) computes tile (bx*128, by*128),
// stores its TRANSPOSE at (j0,i0) — exact by dot-symmetry. Full-line
// nontemporal f32x4 stores; sequential per-row HBM write sweep.
__global__ __launch_bounds__(256, 2) void decoder_mfma_t(const __hip_bfloat16* __restrict__ ZH,
                                                         const __hip_bfloat16* __restrict__ ZL,
                                                         float* __restrict__ A, int n) {
    const short8* Zh8 = (const short8*)ZH;      // row stride = 8 short8 (64 bf16)
    const short8* Zl8 = (const short8*)ZL;
    int tid = threadIdx.x;
    int lane = tid & 63;
    int wid = tid >> 6;
    int wrow = wid >> 1, wcol = wid & 1;
    int i0 = (blockIdx.x << 7) + (wrow << 6);   // A-side rows (bx: fast dim)
    int j0 = (blockIdx.y << 7) + (wcol << 6);   // B-side rows = store rows
    int r16 = lane & 15;
    int kg = lane >> 4;                         // 0..3 : k-group of 8

    f32x4 acc[4][4] = {};

    #pragma unroll
    for (int kc = 0; kc < 2; ++kc) {
        short8 ah[4], al[4], bh[4], bl[4];
        #pragma unroll
        for (int t = 0; t < 4; ++t) {
            int ra = i0 + t * 16 + r16; ra = (ra < n) ? ra : (n - 1);   // clamp OOB loads
            int rb = j0 + t * 16 + r16; rb = (rb < n) ? rb : (n - 1);   // (stores guarded)
            long oa = (long)ra * 8 + kc * 4 + kg;
            long ob = (long)rb * 8 + kc * 4 + kg;
            ah[t] = Zh8[oa];
            al[t] = Zl8[oa];
            bh[t] = Zh8[ob];
            bl[t] = Zl8[ob];
        }
        #pragma unroll
        for (int ti = 0; ti < 4; ++ti)
            #pragma unroll
            for (int tj = 0; tj < 4; ++tj) {
                acc[ti][tj] = __builtin_amdgcn_mfma_f32_16x16x32_bf16(ah[ti], bh[tj], acc[ti][tj], 0, 0, 0);
                acc[ti][tj] = __builtin_amdgcn_mfma_f32_16x16x32_bf16(ah[ti], bl[tj], acc[ti][tj], 0, 0, 0);
                acc[ti][tj] = __builtin_amdgcn_mfma_f32_16x16x32_bf16(al[ti], bh[tj], acc[ti][tj], 0, 0, 0);
            }
    }

    // sigmoid once, in place
    #pragma unroll
    for (int ti = 0; ti < 4; ++ti)
        #pragma unroll
        for (int tj = 0; tj < 4; ++tj)
            #pragma unroll
            for (int q = 0; q < 4; ++q)
                acc[ti][tj][q] = sigf(acc[ti][tj][q]);

    // transposed nontemporal store: A[j0 + tj*16 + r16][i0 + ti*16 + kg*4 .. +3]
    #pragma unroll
    for (int tj = 0; tj < 4; ++tj) {
        int jr = j0 + tj * 16 + r16;
        if (jr < n) {
            long rowb = (long)jr * n;
            #pragma unroll
            for (int ti = 0; ti < 4; ++ti) {
                int c0 = i0 + ti * 16 + (kg << 2);
                if (c0 + 4 <= n) {              // n%4==0: float4 fully in or out
                    __builtin_nontemporal_store(acc[ti][tj], (f32x4*)(A + rowb + c0));
                }
            }
        }
    }
}

extern "C" void kernel_launch(void* const* d_in, const int* in_sizes, int n_in,
                              void* d_out, int out_size, void* d_ws, size_t ws_size,
                              hipStream_t stream) {
    const float* feat     = (const float*)d_in[0];
    const int*   adj_rows = (const int*)d_in[1];
    const int*   adj_cols = (const int*)d_in[2];
    const float* adj_vals = (const float*)d_in[3];
    const float* W1       = (const float*)d_in[4];
    const float* W2       = (const float*)d_in[5];

    float* out  = (float*)d_out;
    float* z    = out;                           // [20000,64]
    float* Arec = out + (long)NN * 64;           // [20000,20000]

    // ws layout: 15.57 MB static.
    float* W12   = (float*)d_ws;                 // 512*64
    float* h     = W12 + 512 * 64;               // [N,64]  (later zh/zl bf16)
    float* hz    = h + (long)NN * 64;            // [N,64]  (hist/base alias here)
    float* val_s = hz + (long)NN * 64;           // [E]
    int*   col_s = (int*)(val_s + EE);           // [E]
    int*   off   = col_s + EE;                   // [N+1]
    // Aliases inside hz: dead until spmm#1 writes hz (stream order)
    int*   hist  = (int*)hz;                     // [HB][N]  1.28 MB
    int*   base  = hist + (long)HB * NN;         // [HB][N]  1.28 MB (ends at 2.56 MB < 5.12)
    // Aliases inside h: written by spmm#2 after h is dead
    __hip_bfloat16* zh = (__hip_bfloat16*)h;     // [N,64] bf16
    __hip_bfloat16* zl = zh + (long)NN * 64;     // [N,64] bf16

    // L0: private histograms ∥ W12 = W1@W2
    fused_hist_g1<<<HB + 8, 256, 0, stream>>>(adj_rows, hist, W1, W2, W12);
    // L1: scan -> off + per-block bases
    scan_hist<<<1, 1024, 0, stream>>>(hist, off, base);
    // L2: scatter (LDS cursors) ∥ h = feat@W12
    fused_scatter_g2<<<HB + 313, 256, 0, stream>>>(adj_rows, adj_cols, adj_vals,
                                                   base, col_s, val_s,
                                                   feat, W12, h);
    // L3/L4: hz = A@h ; z = A@hz (emits split-bf16 z into h's storage)
    spmm_csr64<<<(NN + 3) / 4, 256, 0, stream>>>(off, col_s, val_s, h, hz,
                                                 nullptr, nullptr, NN);
    spmm_csr64<<<(NN + 3) / 4, 256, 0, stream>>>(off, col_s, val_s, hz, z, zh, zl, NN);
    // L5: decoder
    decoder_mfma_t<<<dim3((NN + 127) / 128, (NN + 127) / 128), 256, 0, stream>>>(zh, zl, Arec, NN);
}